// Round 15
// baseline (172068.018 us; speedup 1.0000x reference)
//
#include <hip/hip_runtime.h>

#define TT    1024
#define NTHR  512
#define NWG   256

// ---- per-XCD state block (float offsets within block) ----
#define XB_SZ  65536           // floats per XCD (256 KB)
#define XA0    0               // ahx0: 2 x 8 x 128
#define XA1    2048            // ahx1: 2 x 8 x 128
#define XF0    4096            // fhx0: 2 x 8 x 512
#define XF1    12288           // fhx1: 2 x 8 x 512
#define XP0    20480           // pol0: 8 x 2560
#define XP1    40960           // pol1: 8 x 2560
#define X_ZERO_END 20480

#define O_BARB (8 * XB_SZ)     // barrier block float offset
// bar ints: flags for xcd k at k*64 + r (r=0..31); roster at 1024+k

__device__ __forceinline__ float sigm(float x) { return 1.f / (1.f + __expf(-x)); }

// ---- coherent-read primitives: relaxed agent atomics (compiler-generated,
// bypass L1, served by the shared XCD L2 with dirty-forward; NO asm) ----
__device__ __forceinline__ float ald(const float* p) {
  return __hip_atomic_load(p, __ATOMIC_RELAXED, __HIP_MEMORY_SCOPE_AGENT);
}
__device__ __forceinline__ float2 ald2(const float* p) {
  unsigned long long v = __hip_atomic_load((const unsigned long long*)p,
      __ATOMIC_RELAXED, __HIP_MEMORY_SCOPE_AGENT);
  return make_float2(__uint_as_float((unsigned)v),
                     __uint_as_float((unsigned)(v >> 32)));
}

// ---- dots: suffix A = atomic activations; X = normal (read-only x input) ----
__device__ __forceinline__ float dot_ks(const float* __restrict__ a,
                                        const float* __restrict__ w,
                                        int nq, int ks) {
  float s0=0.f,s1=0.f,s2=0.f,s3=0.f;
  const float4* a4=(const float4*)a; const float4* w4=(const float4*)w;
  #pragma unroll 8
  for (int k = 0; k < nq; ++k) {
    int i4 = (k<<2) + ks;
    float4 av = a4[i4], wv = w4[i4];
    s0=fmaf(av.x,wv.x,s0); s1=fmaf(av.y,wv.y,s1);
    s2=fmaf(av.z,wv.z,s2); s3=fmaf(av.w,wv.w,s3);
  }
  return (s0+s1)+(s2+s3);
}
__device__ __forceinline__ float dotA_ks(const float* a,
                                         const float* __restrict__ w,
                                         int nq, int ks) {
  float s0=0.f,s1=0.f,s2=0.f,s3=0.f;
  const float4* w4=(const float4*)w;
  #pragma unroll 8
  for (int k = 0; k < nq; ++k) {
    int i4 = (k<<2) + ks;
    float2 a0 = ald2(a + i4*4), a1 = ald2(a + i4*4 + 2);
    float4 wv = w4[i4];
    s0=fmaf(a0.x,wv.x,s0); s1=fmaf(a0.y,wv.y,s1);
    s2=fmaf(a1.x,wv.z,s2); s3=fmaf(a1.y,wv.w,s3);
  }
  return (s0+s1)+(s2+s3);
}
// a normal (x), p atomic (pol)
__device__ __forceinline__ float dot3X_ks(const float* __restrict__ a,
                                          const float* pp,
                                          const float* __restrict__ w,
                                          int nq, int ks) {
  float s0=0.f,s1=0.f,s2=0.f,s3=0.f;
  const float4* a4=(const float4*)a; const float4* w4=(const float4*)w;
  #pragma unroll 8
  for (int k = 0; k < nq; ++k) {
    int i4 = (k<<2) + ks;
    float4 av = a4[i4], wv = w4[i4];
    float2 p0 = ald2(pp + i4*4), p1 = ald2(pp + i4*4 + 2);
    s0=fmaf(av.x*p0.x,wv.x,s0); s1=fmaf(av.y*p0.y,wv.y,s1);
    s2=fmaf(av.z*p1.x,wv.z,s2); s3=fmaf(av.w*p1.y,wv.w,s3);
  }
  return (s0+s1)+(s2+s3);
}
// a atomic (state), p atomic (pol)
__device__ __forceinline__ float dot3A_ks(const float* a, const float* pp,
                                          const float* __restrict__ w,
                                          int nq, int ks) {
  float s0=0.f,s1=0.f,s2=0.f,s3=0.f;
  const float4* w4=(const float4*)w;
  #pragma unroll 8
  for (int k = 0; k < nq; ++k) {
    int i4 = (k<<2) + ks;
    float2 a0 = ald2(a + i4*4), a1 = ald2(a + i4*4 + 2);
    float2 p0 = ald2(pp + i4*4), p1 = ald2(pp + i4*4 + 2);
    float4 wv = w4[i4];
    s0=fmaf(a0.x*p0.x,wv.x,s0); s1=fmaf(a0.y*p0.y,wv.y,s1);
    s2=fmaf(a1.x*p1.x,wv.z,s2); s3=fmaf(a1.y*p1.y,wv.w,s3);
  }
  return (s0+s1)+(s2+s3);
}
// 128-float atomic-activation dot (pol phases)
__device__ __forceinline__ float dotA_full(const float* a,
                                           const float* __restrict__ w) {
  float s0=0.f,s1=0.f,s2=0.f,s3=0.f;
  const float4* w4=(const float4*)w;
  #pragma unroll 8
  for (int k = 0; k < 32; ++k) {
    float2 a0 = ald2(a + k*4), a1 = ald2(a + k*4 + 2);
    float4 wv = w4[k];
    s0=fmaf(a0.x,wv.x,s0); s1=fmaf(a0.y,wv.y,s1);
    s2=fmaf(a1.x,wv.z,s2); s3=fmaf(a1.y,wv.w,s3);
  }
  return (s0+s1)+(s2+s3);
}

// ---- intra-XCD barrier: parallel flag stores + parallel poll. No RMW chain,
// no acquire, no cache maintenance. Correctness: normal data stores drain to
// the shared XCD L2 at __syncthreads (per-wave vmcnt) BEFORE the flag store;
// consumers' data reads are relaxed-agent atomics (bypass L1, dirty-forward
// from the same L2), issued only after the poll observes all flags == e.
__device__ __forceinline__ void xbar(int* flags, int r, int e, int tid) {
  __syncthreads();
  if (tid == 0) {
    __hip_atomic_store(&flags[r], e, __ATOMIC_RELAXED, __HIP_MEMORY_SCOPE_AGENT);
    for (;;) {
      bool ok = true;
      #pragma unroll
      for (int i = 0; i < 32; ++i) {
        int v = __hip_atomic_load(&flags[i], __ATOMIC_RELAXED,
                                  __HIP_MEMORY_SCOPE_AGENT);
        ok &= (v >= e);
      }
      if (ok) break;
      __builtin_amdgcn_s_sleep(1);
    }
    asm volatile("" ::: "memory");
  }
  __syncthreads();
}

struct Params {
  const float* x;
  const float *aW_ih0, *aW_hh0, *ab_ih0, *ab_hh0, *pW0, *pb0, *fW_ih0, *fW_hh0, *fb0;
  const float *aW_ih1, *aW_hh1, *ab_ih1, *ab_hh1, *pW1, *pb1, *fW_ih1, *fW_hh1, *fb1;
  float* out;
  float* ws;
};

__global__ __launch_bounds__(NTHR, 1)
void arnn_kernel(Params p) {
  extern __shared__ float lds[];     // dummy 84 KB: forces 1 WG/CU (pigeonhole)
  __shared__ int s_rank;
  const int tid = threadIdx.x;
  float* __restrict__ ws = p.ws;

  int xcd;
  asm volatile("s_getreg_b32 %0, hwreg(HW_REG_XCC_ID)" : "=s"(xcd));
  xcd &= 7;

  int* bar = (int*)(ws + O_BARB);
  if (tid == 0)
    s_rank = __hip_atomic_fetch_add(&bar[1024 + xcd], 1,
                                    __ATOMIC_RELAXED, __HIP_MEMORY_SCOPE_AGENT);
  __syncthreads();
  const int r = s_rank;              // rank 0..31 within this XCD
  int* flags = &bar[xcd * 64];

  float* xb = ws + (size_t)xcd * XB_SZ;
  const int b0 = xcd * 8;            // this XCD owns batches b0..b0+7

  // zero this XCD's recurrent state (normal stores -> dirty zeros in own L2)
  for (int i = r * NTHR + tid; i < X_ZERO_END; i += 32 * NTHR) xb[i] = 0.f;

  // ---- thread maps (R12-proven) ----
  const int lane = tid & 63;
  const int ks   = tid & 3;
  const int jj = tid >> 7, blL = (tid >> 4) & 7, q = (tid >> 2) & 3;
  const int jL = r * 4 + jj;
  const bool cell = (tid & 15) == 0;
  const int c4 = tid >> 5, blA = (tid >> 2) & 7;
  const int cA = r * 16 + c4;
  const int nAr = tid >> 3, blP = tid & 7;
  const int nA = r * 80 + nAr;
  const int nB = r * 80 + 64 + nAr;  // valid if tid < 128

  float bi0=0,bf0=0,bg0=0,bo0=0, bi1=0,bf1=0,bg1=0,bo1=0;
  if (cell) {
    bi0 = p.ab_ih0[0*128+jL] + p.ab_hh0[0*128+jL];
    bf0 = p.ab_ih0[1*128+jL] + p.ab_hh0[1*128+jL];
    bg0 = p.ab_ih0[2*128+jL] + p.ab_hh0[2*128+jL];
    bo0 = p.ab_ih0[3*128+jL] + p.ab_hh0[3*128+jL];
    bi1 = p.ab_ih1[0*128+jL] + p.ab_hh1[0*128+jL];
    bf1 = p.ab_ih1[1*128+jL] + p.ab_hh1[1*128+jL];
    bg1 = p.ab_ih1[2*128+jL] + p.ab_hh1[2*128+jL];
    bo1 = p.ab_ih1[3*128+jL] + p.ab_hh1[3*128+jL];
  }
  const float fb0c = p.fb0[cA], fb1c = p.fb1[cA];
  const float pb0a = p.pb0[nA], pb1a = p.pb1[nA];
  float pb0b = 0.f, pb1b = 0.f;
  if (tid < 128) { pb0b = p.pb0[nB]; pb1b = p.pb1[nB]; }

  // weight row pointers (normal cached loads; never invalidated -> L2-warm)
  const int rowL = q * 128 + jL;
  const float* wih0 = p.aW_ih0 + (size_t)rowL * 1152;
  const float* whh0 = p.aW_hh0 + (size_t)rowL * 128;
  const float* wih1 = p.aW_ih1 + (size_t)rowL * 1152;
  const float* whh1 = p.aW_hh1 + (size_t)rowL * 128;
  const float* fwi0 = p.fW_ih0 + (size_t)cA * 512;
  const float* fwh0 = p.fW_hh0 + (size_t)cA * 512;
  const float* fwi1 = p.fW_ih1 + (size_t)cA * 512;
  const float* fwh1 = p.fW_hh1 + (size_t)cA * 512;

  float creg0 = 0.f, creg1 = 0.f;    // LSTM cell states (thread-resident)

  int e = 1;
  xbar(flags, r, e, tid);

  for (int t = 0; t < TT; ++t) {
    const int old = t & 1, nw = old ^ 1;
    float* ahx0_o = xb + XA0 + old * 1024;
    float* ahx0_n = xb + XA0 + nw  * 1024;
    float* ahx1_o = xb + XA1 + old * 1024;
    float* ahx1_n = xb + XA1 + nw  * 1024;
    float* fhx0_o = xb + XF0 + old * 4096;
    float* fhx0_n = xb + XF0 + nw  * 4096;
    float* fhx1_o = xb + XF1 + old * 4096;
    float* fhx1_n = xb + XF1 + nw  * 4096;
    float* pol0   = xb + XP0;
    float* pol1   = xb + XP1;
    const float* xt = p.x + ((size_t)t * 64 + b0) * 512;

    // ---- P0: LSTM0 ----
    {
      float s = dot_ks (xt     + blL * 512, wih0,        32, ks)
              + dotA_ks(fhx0_o + blL * 512, wih0 + 512,  32, ks)
              + dotA_ks(ahx1_o + blL * 128, wih0 + 1024,  8, ks)
              + dotA_ks(ahx0_o + blL * 128, whh0,         8, ks);
      s += __shfl_xor(s, 1); s += __shfl_xor(s, 2);
      float gi = __shfl(s,(lane&48)+0),  gf = __shfl(s,(lane&48)+4);
      float gg = __shfl(s,(lane&48)+8),  go = __shfl(s,(lane&48)+12);
      if (cell) {
        gi += bi0; gf += bf0; gg += bg0; go += bo0;
        float c2 = sigm(gf) * creg0 + sigm(gi) * tanhf(gg);
        creg0 = c2;
        ahx0_n[blL * 128 + jL] = sigm(go) * tanhf(c2);
      }
    }
    ++e; xbar(flags, r, e, tid);

    // ---- P1: pol0 ----
    {
      pol0[blP * 2560 + nA] = pb0a +
          dotA_full(ahx0_n + blP * 128, p.pW0 + (size_t)nA * 128);
      if (tid < 128)
        pol0[blP * 2560 + nB] = pb0b +
            dotA_full(ahx0_n + blP * 128, p.pW0 + (size_t)nB * 128);
    }
    ++e; xbar(flags, r, e, tid);

    // ---- P2: aRNN0 ----
    {
      const float* pr = pol0 + blA * 2560;
      float sig = dot3X_ks(xt     + blA * 512, pr,       fwi0, 32, ks);
      float shg = dot3A_ks(fhx0_o + blA * 512, pr + 512, fwh0, 32, ks);
      sig += __shfl_xor(sig, 1); sig += __shfl_xor(sig, 2);
      shg += __shfl_xor(shg, 1); shg += __shfl_xor(shg, 2);
      if (ks == 0) {
        float v = tanhf(sig * ald(pr + 1024 + cA) + fb0c * ald(pr + 2048 + cA)
                      + shg * ald(pr + 1536 + cA));
        fhx0_n[blA * 512 + cA] = v;
      }
    }
    ++e; xbar(flags, r, e, tid);

    // ---- P3: LSTM1 ----
    {
      float s = dotA_ks(fhx0_n + blL * 512, wih1,        32, ks)
              + dotA_ks(fhx1_o + blL * 512, wih1 + 512,  32, ks)
              + dotA_ks(ahx0_n + blL * 128, wih1 + 1024,  8, ks)
              + dotA_ks(ahx1_o + blL * 128, whh1,         8, ks);
      s += __shfl_xor(s, 1); s += __shfl_xor(s, 2);
      float gi = __shfl(s,(lane&48)+0),  gf = __shfl(s,(lane&48)+4);
      float gg = __shfl(s,(lane&48)+8),  go = __shfl(s,(lane&48)+12);
      if (cell) {
        gi += bi1; gf += bf1; gg += bg1; go += bo1;
        float c2 = sigm(gf) * creg1 + sigm(gi) * tanhf(gg);
        creg1 = c2;
        ahx1_n[blL * 128 + jL] = sigm(go) * tanhf(c2);
      }
    }
    ++e; xbar(flags, r, e, tid);

    // ---- P4: pol1 ----
    {
      pol1[blP * 2560 + nA] = pb1a +
          dotA_full(ahx1_n + blP * 128, p.pW1 + (size_t)nA * 128);
      if (tid < 128)
        pol1[blP * 2560 + nB] = pb1b +
            dotA_full(ahx1_n + blP * 128, p.pW1 + (size_t)nB * 128);
    }
    ++e; xbar(flags, r, e, tid);

    // ---- P5: aRNN1 + output ----
    {
      const float* pr = pol1 + blA * 2560;
      float sig = dot3A_ks(fhx0_n + blA * 512, pr,       fwi1, 32, ks);
      float shg = dot3A_ks(fhx1_o + blA * 512, pr + 512, fwh1, 32, ks);
      sig += __shfl_xor(sig, 1); sig += __shfl_xor(sig, 2);
      shg += __shfl_xor(shg, 1); shg += __shfl_xor(shg, 2);
      if (ks == 0) {
        float v = tanhf(sig * ald(pr + 1024 + cA) + fb1c * ald(pr + 2048 + cA)
                      + shg * ald(pr + 1536 + cA));
        fhx1_n[blA * 512 + cA] = v;
        p.out[((size_t)t * 64 + b0 + blA) * 512 + cA] = v;
      }
    }
    ++e; xbar(flags, r, e, tid);
  }
  (void)lds;
}

extern "C" void kernel_launch(void* const* d_in, const int* in_sizes, int n_in,
                              void* d_out, int out_size, void* d_ws, size_t ws_size,
                              hipStream_t stream) {
  Params prm;
  prm.x      = (const float*)d_in[0];
  prm.aW_ih0 = (const float*)d_in[1];
  prm.aW_hh0 = (const float*)d_in[2];
  prm.ab_ih0 = (const float*)d_in[3];
  prm.ab_hh0 = (const float*)d_in[4];
  prm.pW0    = (const float*)d_in[5];
  prm.pb0    = (const float*)d_in[6];
  prm.fW_ih0 = (const float*)d_in[7];
  prm.fW_hh0 = (const float*)d_in[8];
  prm.fb0    = (const float*)d_in[9];
  prm.aW_ih1 = (const float*)d_in[10];
  prm.aW_hh1 = (const float*)d_in[11];
  prm.ab_ih1 = (const float*)d_in[12];
  prm.ab_hh1 = (const float*)d_in[13];
  prm.pW1    = (const float*)d_in[14];
  prm.pb1    = (const float*)d_in[15];
  prm.fW_ih1 = (const float*)d_in[16];
  prm.fW_hh1 = (const float*)d_in[17];
  prm.fb1    = (const float*)d_in[18];
  prm.out    = (float*)d_out;
  prm.ws     = (float*)d_ws;

  // zero flags + roster (per launch -> deterministic replays)
  hipMemsetAsync((char*)d_ws + (size_t)O_BARB * 4, 0, 8192, stream);

  static int lds_bytes = 84 * 1024;   // forces 1 WG/CU (pigeonhole: 32 WG/XCD)
  hipFuncSetAttribute((const void*)arnn_kernel,
                      hipFuncAttributeMaxDynamicSharedMemorySize, lds_bytes);

  void* kargs[] = { (void*)&prm };
  hipLaunchCooperativeKernel((const void*)arnn_kernel, dim3(NWG), dim3(NTHR),
                             kargs, lds_bytes, stream);
}

// Round 16
// 120389.001 us; speedup vs baseline: 1.4293x; 1.4293x over previous
//
#include <hip/hip_runtime.h>

#define TT    1024
#define NTHR  512
#define NWG   256

// ---- per-XCD state block (float offsets within block) ----
#define XB_SZ  65536           // floats per XCD (256 KB)
#define XA0    0               // ahx0: 2 x 8 x 128
#define XA1    2048            // ahx1: 2 x 8 x 128
#define XF0    4096            // fhx0: 2 x 8 x 512
#define XF1    12288           // fhx1: 2 x 8 x 512
#define XP0    20480           // pol0: 8 x 2560
#define XP1    40960           // pol1: 8 x 2560
#define X_ZERO_END 20480

#define O_BARB (8 * XB_SZ)     // barrier block float offset (byte 2 MB)
// bar ints: flags for xcd k at k*128 + r (r=0..31); roster at 4096+k

__device__ __forceinline__ float sigm(float x) { return 1.f / (1.f + __expf(-x)); }

// K-sliced dot: thread ks takes float4 #(k*4+ks); 4 lanes cover 64B contiguous.
__device__ __forceinline__ float dot_ks(const float* __restrict__ a,
                                        const float* __restrict__ w,
                                        int nq, int ks) {
  float s0=0.f,s1=0.f,s2=0.f,s3=0.f;
  const float4* a4=(const float4*)a; const float4* w4=(const float4*)w;
  #pragma unroll 8
  for (int k = 0; k < nq; ++k) {
    int i4 = (k<<2) + ks;
    float4 av = a4[i4], wv = w4[i4];
    s0=fmaf(av.x,wv.x,s0); s1=fmaf(av.y,wv.y,s1);
    s2=fmaf(av.z,wv.z,s2); s3=fmaf(av.w,wv.w,s3);
  }
  return (s0+s1)+(s2+s3);
}
__device__ __forceinline__ float dot3_ks(const float* __restrict__ a,
                                         const float* __restrict__ pp,
                                         const float* __restrict__ w,
                                         int nq, int ks) {
  float s0=0.f,s1=0.f,s2=0.f,s3=0.f;
  const float4* a4=(const float4*)a; const float4* p4=(const float4*)pp;
  const float4* w4=(const float4*)w;
  #pragma unroll 8
  for (int k = 0; k < nq; ++k) {
    int i4 = (k<<2) + ks;
    float4 av = a4[i4], pv = p4[i4], wv = w4[i4];
    s0=fmaf(av.x*pv.x,wv.x,s0); s1=fmaf(av.y*pv.y,wv.y,s1);
    s2=fmaf(av.z*pv.z,wv.z,s2); s3=fmaf(av.w*pv.w,wv.w,s3);
  }
  return (s0+s1)+(s2+s3);
}
__device__ __forceinline__ float dot_full(const float* __restrict__ a,
                                          const float* __restrict__ w) {
  float s0=0.f,s1=0.f,s2=0.f,s3=0.f;
  const float4* a4=(const float4*)a; const float4* w4=(const float4*)w;
  #pragma unroll 8
  for (int k = 0; k < 32; ++k) {
    float4 av = a4[k], wv = w4[k];
    s0=fmaf(av.x,wv.x,s0); s1=fmaf(av.y,wv.y,s1);
    s2=fmaf(av.z,wv.z,s2); s3=fmaf(av.w,wv.w,s3);
  }
  return (s0+s1)+(s2+s3);
}

// ---- intra-XCD barrier: PARALLEL flag stores (no serialized RMW chain) +
// poll + ONE acquire. Correctness: producer normal stores drain to the shared
// XCD L2 at __syncthreads (per-wave vmcnt) before the flag store; the acquire
// after the poll invalidates stale L1 / clean L2 lines (dirty same-L2
// activation lines survive); consumers then read fresh data from shared L2.
__device__ __forceinline__ void xbar(int* flags, int r, int e, int tid) {
  __syncthreads();
  if (tid == 0) {
    __hip_atomic_store(&flags[r], e, __ATOMIC_RELAXED, __HIP_MEMORY_SCOPE_AGENT);
    for (;;) {
      bool ok = true;
      #pragma unroll
      for (int i = 0; i < 32; ++i) {
        int v = __hip_atomic_load(&flags[i], __ATOMIC_RELAXED,
                                  __HIP_MEMORY_SCOPE_AGENT);
        ok &= (v >= e);
      }
      if (ok) break;
      __builtin_amdgcn_s_sleep(1);
    }
    (void)__hip_atomic_load(&flags[r], __ATOMIC_ACQUIRE,
                            __HIP_MEMORY_SCOPE_AGENT);
  }
  __syncthreads();
}

struct Params {
  const float* x;
  const float *aW_ih0, *aW_hh0, *ab_ih0, *ab_hh0, *pW0, *pb0, *fW_ih0, *fW_hh0, *fb0;
  const float *aW_ih1, *aW_hh1, *ab_ih1, *ab_hh1, *pW1, *pb1, *fW_ih1, *fW_hh1, *fb1;
  float* out;
  float* ws;
};

__global__ __launch_bounds__(NTHR, 1)
void arnn_kernel(Params p) {
  extern __shared__ float lds[];     // dummy 84 KB: forces 1 WG/CU (pigeonhole)
  __shared__ int s_rank;
  const int tid = threadIdx.x;
  float* __restrict__ ws = p.ws;

  int xcd;
  asm volatile("s_getreg_b32 %0, hwreg(HW_REG_XCC_ID)" : "=s"(xcd));
  xcd &= 7;

  int* bar = (int*)(ws + O_BARB);
  if (tid == 0)
    s_rank = __hip_atomic_fetch_add(&bar[4096 + xcd], 1,
                                    __ATOMIC_RELAXED, __HIP_MEMORY_SCOPE_AGENT);
  __syncthreads();
  const int r = s_rank;              // rank 0..31 within this XCD
  int* flags = &bar[xcd * 128];

  float* xb = ws + (size_t)xcd * XB_SZ;
  const int b0 = xcd * 8;            // this XCD owns batches b0..b0+7

  // zero this XCD's recurrent state
  for (int i = r * NTHR + tid; i < X_ZERO_END; i += 32 * NTHR) xb[i] = 0.f;

  // ---- thread maps (R12-proven) ----
  const int lane = tid & 63;
  const int ks   = tid & 3;
  const int jj = tid >> 7, blL = (tid >> 4) & 7, q = (tid >> 2) & 3;
  const int jL = r * 4 + jj;
  const bool cell = (tid & 15) == 0;
  const int c4 = tid >> 5, blA = (tid >> 2) & 7;
  const int cA = r * 16 + c4;
  const int nAr = tid >> 3, blP = tid & 7;
  const int nA = r * 80 + nAr;
  const int nB = r * 80 + 64 + nAr;  // valid if tid < 128

  float bi0=0,bf0=0,bg0=0,bo0=0, bi1=0,bf1=0,bg1=0,bo1=0;
  if (cell) {
    bi0 = p.ab_ih0[0*128+jL] + p.ab_hh0[0*128+jL];
    bf0 = p.ab_ih0[1*128+jL] + p.ab_hh0[1*128+jL];
    bg0 = p.ab_ih0[2*128+jL] + p.ab_hh0[2*128+jL];
    bo0 = p.ab_ih0[3*128+jL] + p.ab_hh0[3*128+jL];
    bi1 = p.ab_ih1[0*128+jL] + p.ab_hh1[0*128+jL];
    bf1 = p.ab_ih1[1*128+jL] + p.ab_hh1[1*128+jL];
    bg1 = p.ab_ih1[2*128+jL] + p.ab_hh1[2*128+jL];
    bo1 = p.ab_ih1[3*128+jL] + p.ab_hh1[3*128+jL];
  }
  const float fb0c = p.fb0[cA], fb1c = p.fb1[cA];
  const float pb0a = p.pb0[nA], pb1a = p.pb1[nA];
  float pb0b = 0.f, pb1b = 0.f;
  if (tid < 128) { pb0b = p.pb0[nB]; pb1b = p.pb1[nB]; }

  // ---- streamed weight row pointers (normal cached loads) ----
  const int rowL = q * 128 + jL;
  const float* wih0 = p.aW_ih0 + (size_t)rowL * 1152;
  const float* whh0 = p.aW_hh0 + (size_t)rowL * 128;
  const float* wih1 = p.aW_ih1 + (size_t)rowL * 1152;
  const float* whh1 = p.aW_hh1 + (size_t)rowL * 128;
  const float* fwi0 = p.fW_ih0 + (size_t)cA * 512;
  const float* fwh0 = p.fW_hh0 + (size_t)cA * 512;
  const float* fwi1 = p.fW_ih1 + (size_t)cA * 512;
  const float* fwh1 = p.fW_hh1 + (size_t)cA * 512;

  float creg0 = 0.f, creg1 = 0.f;    // LSTM cell states (thread-resident)

  int e = 1;
  xbar(flags, r, e, tid);

  for (int t = 0; t < TT; ++t) {
    const int old = t & 1, nw = old ^ 1;
    float* ahx0_o = xb + XA0 + old * 1024;
    float* ahx0_n = xb + XA0 + nw  * 1024;
    float* ahx1_o = xb + XA1 + old * 1024;
    float* ahx1_n = xb + XA1 + nw  * 1024;
    float* fhx0_o = xb + XF0 + old * 4096;
    float* fhx0_n = xb + XF0 + nw  * 4096;
    float* fhx1_o = xb + XF1 + old * 4096;
    float* fhx1_n = xb + XF1 + nw  * 4096;
    float* pol0   = xb + XP0;
    float* pol1   = xb + XP1;
    const float* xt = p.x + ((size_t)t * 64 + b0) * 512;

    // ---- P0: LSTM0 ----
    {
      float s = dot_ks(xt     + blL * 512, wih0,        32, ks)
              + dot_ks(fhx0_o + blL * 512, wih0 + 512,  32, ks)
              + dot_ks(ahx1_o + blL * 128, wih0 + 1024,  8, ks)
              + dot_ks(ahx0_o + blL * 128, whh0,         8, ks);
      s += __shfl_xor(s, 1); s += __shfl_xor(s, 2);
      float gi = __shfl(s,(lane&48)+0),  gf = __shfl(s,(lane&48)+4);
      float gg = __shfl(s,(lane&48)+8),  go = __shfl(s,(lane&48)+12);
      if (cell) {
        gi += bi0; gf += bf0; gg += bg0; go += bo0;
        float c2 = sigm(gf) * creg0 + sigm(gi) * tanhf(gg);
        creg0 = c2;
        ahx0_n[blL * 128 + jL] = sigm(go) * tanhf(c2);
      }
    }
    ++e; xbar(flags, r, e, tid);

    // ---- P1: pol0 ----
    {
      pol0[blP * 2560 + nA] = pb0a +
          dot_full(ahx0_n + blP * 128, p.pW0 + (size_t)nA * 128);
      if (tid < 128)
        pol0[blP * 2560 + nB] = pb0b +
            dot_full(ahx0_n + blP * 128, p.pW0 + (size_t)nB * 128);
    }
    ++e; xbar(flags, r, e, tid);

    // ---- P2: aRNN0 ----
    {
      const float* pr = pol0 + blA * 2560;
      float sig = dot3_ks(xt     + blA * 512, pr,       fwi0, 32, ks);
      float shg = dot3_ks(fhx0_o + blA * 512, pr + 512, fwh0, 32, ks);
      sig += __shfl_xor(sig, 1); sig += __shfl_xor(sig, 2);
      shg += __shfl_xor(shg, 1); shg += __shfl_xor(shg, 2);
      if (ks == 0) {
        float v = tanhf(sig * pr[1024 + cA] + fb0c * pr[2048 + cA]
                      + shg * pr[1536 + cA]);
        fhx0_n[blA * 512 + cA] = v;
      }
    }
    ++e; xbar(flags, r, e, tid);

    // ---- P3: LSTM1 ----
    {
      float s = dot_ks(fhx0_n + blL * 512, wih1,        32, ks)
              + dot_ks(fhx1_o + blL * 512, wih1 + 512,  32, ks)
              + dot_ks(ahx0_n + blL * 128, wih1 + 1024,  8, ks)
              + dot_ks(ahx1_o + blL * 128, whh1,         8, ks);
      s += __shfl_xor(s, 1); s += __shfl_xor(s, 2);
      float gi = __shfl(s,(lane&48)+0),  gf = __shfl(s,(lane&48)+4);
      float gg = __shfl(s,(lane&48)+8),  go = __shfl(s,(lane&48)+12);
      if (cell) {
        gi += bi1; gf += bf1; gg += bg1; go += bo1;
        float c2 = sigm(gf) * creg1 + sigm(gi) * tanhf(gg);
        creg1 = c2;
        ahx1_n[blL * 128 + jL] = sigm(go) * tanhf(c2);
      }
    }
    ++e; xbar(flags, r, e, tid);

    // ---- P4: pol1 ----
    {
      pol1[blP * 2560 + nA] = pb1a +
          dot_full(ahx1_n + blP * 128, p.pW1 + (size_t)nA * 128);
      if (tid < 128)
        pol1[blP * 2560 + nB] = pb1b +
            dot_full(ahx1_n + blP * 128, p.pW1 + (size_t)nB * 128);
    }
    ++e; xbar(flags, r, e, tid);

    // ---- P5: aRNN1 + output ----
    {
      const float* pr = pol1 + blA * 2560;
      float sig = dot3_ks(fhx0_n + blA * 512, pr,       fwi1, 32, ks);
      float shg = dot3_ks(fhx1_o + blA * 512, pr + 512, fwh1, 32, ks);
      sig += __shfl_xor(sig, 1); sig += __shfl_xor(sig, 2);
      shg += __shfl_xor(shg, 1); shg += __shfl_xor(shg, 2);
      if (ks == 0) {
        float v = tanhf(sig * pr[1024 + cA] + fb1c * pr[2048 + cA]
                      + shg * pr[1536 + cA]);
        fhx1_n[blA * 512 + cA] = v;
        p.out[((size_t)t * 64 + b0 + blA) * 512 + cA] = v;
      }
    }
    ++e; xbar(flags, r, e, tid);
  }
  (void)lds;
}

extern "C" void kernel_launch(void* const* d_in, const int* in_sizes, int n_in,
                              void* d_out, int out_size, void* d_ws, size_t ws_size,
                              hipStream_t stream) {
  Params prm;
  prm.x      = (const float*)d_in[0];
  prm.aW_ih0 = (const float*)d_in[1];
  prm.aW_hh0 = (const float*)d_in[2];
  prm.ab_ih0 = (const float*)d_in[3];
  prm.ab_hh0 = (const float*)d_in[4];
  prm.pW0    = (const float*)d_in[5];
  prm.pb0    = (const float*)d_in[6];
  prm.fW_ih0 = (const float*)d_in[7];
  prm.fW_hh0 = (const float*)d_in[8];
  prm.fb0    = (const float*)d_in[9];
  prm.aW_ih1 = (const float*)d_in[10];
  prm.aW_hh1 = (const float*)d_in[11];
  prm.ab_ih1 = (const float*)d_in[12];
  prm.ab_hh1 = (const float*)d_in[13];
  prm.pW1    = (const float*)d_in[14];
  prm.pb1    = (const float*)d_in[15];
  prm.fW_ih1 = (const float*)d_in[16];
  prm.fW_hh1 = (const float*)d_in[17];
  prm.fb1    = (const float*)d_in[18];
  prm.out    = (float*)d_out;
  prm.ws     = (float*)d_ws;

  // zero flags + roster (per launch -> deterministic replays)
  hipMemsetAsync((char*)d_ws + (size_t)O_BARB * 4, 0, 32768, stream);

  static int lds_bytes = 84 * 1024;   // forces 1 WG/CU (pigeonhole: 32 WG/XCD)
  hipFuncSetAttribute((const void*)arnn_kernel,
                      hipFuncAttributeMaxDynamicSharedMemorySize, lds_bytes);

  void* kargs[] = { (void*)&prm };
  hipLaunchCooperativeKernel((const void*)arnn_kernel, dim3(NWG), dim3(NTHR),
                             kargs, lds_bytes, stream);
}